// Round 1
// baseline (4188.390 us; speedup 1.0000x reference)
//
#include <hip/hip_runtime.h>
#include <hip/hip_bf16.h>
#include <math.h>

#define D_MODEL 1024
#define SEQ 2048
#define NH 16
#define DH 64
#define DFF 4096
#define ROWS 4096  // B*S

// ---------------- RMSNorm: one block per row, 256 threads * float4 ----------------
__global__ __launch_bounds__(256) void rmsnorm_k(const float* __restrict__ x,
                                                 const float* __restrict__ g,
                                                 float* __restrict__ o) {
  const int r = blockIdx.x;
  const int t = threadIdx.x;
  const float4 xv = ((const float4*)(x + (size_t)r * D_MODEL))[t];
  float ss = xv.x * xv.x + xv.y * xv.y + xv.z * xv.z + xv.w * xv.w;
#pragma unroll
  for (int m = 32; m >= 1; m >>= 1) ss += __shfl_xor(ss, m);
  __shared__ float wp[4];
  if ((t & 63) == 0) wp[t >> 6] = ss;
  __syncthreads();
  const float tot = wp[0] + wp[1] + wp[2] + wp[3];
  const float inv = rsqrtf(tot * (1.0f / D_MODEL) + 1e-5f);
  const float4 gv = ((const float4*)g)[t];
  float4 ov;
  ov.x = xv.x * inv * gv.x;
  ov.y = xv.y * inv * gv.y;
  ov.z = xv.z * inv * gv.z;
  ov.w = xv.w * inv * gv.w;
  ((float4*)(o + (size_t)r * D_MODEL))[t] = ov;
}

// ---------------- RoPE in-place on Q and K ----------------
__global__ __launch_bounds__(256) void rope_k(float* __restrict__ Q, float* __restrict__ K) {
  const int idx = blockIdx.x * 256 + threadIdx.x;  // ROWS*512 pairs
  const int r = idx >> 9;
  const int p = idx & 511;
  const int head = p >> 5;
  const int i = p & 31;
  const int s = r & (SEQ - 1);
  const float inv_freq = powf(10000.0f, -(float)i * (1.0f / 32.0f));
  const float ang = (float)s * inv_freq;
  float sn, cs;
  sincosf(ang, &sn, &cs);
  const size_t base = (size_t)r * D_MODEL + head * DH + 2 * i;
  const float q1 = Q[base], q2 = Q[base + 1];
  Q[base] = q1 * cs - q2 * sn;
  Q[base + 1] = q2 * cs + q1 * sn;
  const float k1 = K[base], k2 = K[base + 1];
  K[base] = k1 * cs - k2 * sn;
  K[base + 1] = k2 * cs + k1 * sn;
}

// ---------------- Flash-style causal attention ----------------
// grid: (S/64, B*H). Block 256 = 4 waves; wave w owns 16 q-rows.
// lane roles: score phase lane = key j; PV/output phase lane = dim d.
__global__ __launch_bounds__(256) void attn_k(const float* __restrict__ Q,
                                              const float* __restrict__ Kk,
                                              const float* __restrict__ V,
                                              float* __restrict__ O) {
  __shared__ float Qs[64][68];   // [qrow][d], pad 68: broadcast reads + f4 stores ok
  __shared__ float KsT[64][69];  // [d][key], pad 69: conflict-free scatter store + read
  __shared__ float Vs[64][68];   // [key][d]
  __shared__ float Ps[4][64];    // per-wave P row
  const int qt = blockIdx.x;
  const int bh = blockIdx.y;
  const int b = bh >> 4, hh = bh & 15;
  const int q0 = qt << 6;
  const int t = threadIdx.x;
  const int lane = t & 63, w = t >> 6;
  const size_t hb = (size_t)b * SEQ * D_MODEL + hh * DH;
  const float* Qb = Q + hb;
  const float* Kb = Kk + hb;
  const float* Vb = V + hb;
  float* Ob = O + hb;
  const int j = t >> 2;
  const int d0 = (t & 3) << 4;
#pragma unroll
  for (int c = 0; c < 4; ++c) {
    float4 qv = *(const float4*)&Qb[(size_t)(q0 + j) * D_MODEL + d0 + c * 4];
    qv.x *= 0.125f; qv.y *= 0.125f; qv.z *= 0.125f; qv.w *= 0.125f;  // 1/sqrt(64)
    *(float4*)&Qs[j][d0 + c * 4] = qv;
  }
  float acc[16], mr[16], lr[16];
#pragma unroll
  for (int r = 0; r < 16; ++r) { acc[r] = 0.f; mr[r] = -INFINITY; lr[r] = 0.f; }
  const int ktmax = q0 >> 6;
  for (int kt = 0; kt <= ktmax; ++kt) {
    __syncthreads();
#pragma unroll
    for (int c = 0; c < 4; ++c) {
      const float4 kv = *(const float4*)&Kb[(size_t)(kt * 64 + j) * D_MODEL + d0 + c * 4];
      KsT[d0 + c * 4 + 0][j] = kv.x;
      KsT[d0 + c * 4 + 1][j] = kv.y;
      KsT[d0 + c * 4 + 2][j] = kv.z;
      KsT[d0 + c * 4 + 3][j] = kv.w;
      *(float4*)&Vs[j][d0 + c * 4] =
          *(const float4*)&Vb[(size_t)(kt * 64 + j) * D_MODEL + d0 + c * 4];
    }
    __syncthreads();
    const bool diag = (kt == ktmax);
#pragma unroll
    for (int r = 0; r < 16; ++r) {
      const int lrow = w * 16 + r;
      float s = 0.f;
#pragma unroll 8
      for (int d = 0; d < 64; ++d) s += Qs[lrow][d] * KsT[d][lane];
      if (diag && lane > lrow) s = -INFINITY;
      float tm = s;
#pragma unroll
      for (int msk = 32; msk >= 1; msk >>= 1) tm = fmaxf(tm, __shfl_xor(tm, msk));
      const float nm = fmaxf(mr[r], tm);
      const float p = __expf(s - nm);
      float ts = p;
#pragma unroll
      for (int msk = 32; msk >= 1; msk >>= 1) ts += __shfl_xor(ts, msk);
      const float rsc = __expf(mr[r] - nm);
      mr[r] = nm;
      lr[r] = lr[r] * rsc + ts;
      Ps[w][lane] = p;
      float a = acc[r] * rsc;
#pragma unroll 8
      for (int jj = 0; jj < 64; ++jj) a += Ps[w][jj] * Vs[jj][lane];
      acc[r] = a;
    }
  }
#pragma unroll
  for (int r = 0; r < 16; ++r) {
    const int row = q0 + w * 16 + r;
    Ob[(size_t)row * D_MODEL + lane] = acc[r] / lr[r];
  }
}

// ---------------- fp32 GEMM, 64x64 tile, BK=16, 4x4 per thread ----------------
// MODE 0: C = A@B ; MODE 1: C = R + A@B ; MODE 2: C = silu(A@B) * (A@B2)
template <int MODE>
__global__ __launch_bounds__(256) void gemm_k(const float* __restrict__ A,
                                              const float* __restrict__ B,
                                              const float* __restrict__ B2,
                                              const float* __restrict__ R,
                                              float* __restrict__ C,
                                              int M, int N, int K) {
  __shared__ float As[16][68];  // [k][m] transposed
  __shared__ float Bs[16][68];  // [k][n]
  __shared__ float Bs2[16][68];
  const int t = threadIdx.x;
  const int tx = t & 15, ty = t >> 4;
  const int n0 = blockIdx.x << 6, m0 = blockIdx.y << 6;
  float acc[4][4] = {};
  float acc2[4][4] = {};
  const int am = t >> 2, ak = (t & 3) << 2;
  const int lk = t >> 4, ln = (t & 15) << 2;
  const int nt = K >> 4;
  for (int kt = 0; kt < nt; ++kt) {
    __syncthreads();
    const float4 av = *(const float4*)&A[(size_t)(m0 + am) * K + (kt << 4) + ak];
    As[ak + 0][am] = av.x;
    As[ak + 1][am] = av.y;
    As[ak + 2][am] = av.z;
    As[ak + 3][am] = av.w;
    *(float4*)&Bs[lk][ln] = *(const float4*)&B[(size_t)((kt << 4) + lk) * N + n0 + ln];
    if (MODE == 2)
      *(float4*)&Bs2[lk][ln] = *(const float4*)&B2[(size_t)((kt << 4) + lk) * N + n0 + ln];
    __syncthreads();
#pragma unroll
    for (int k = 0; k < 16; ++k) {
      const float4 a = *(const float4*)&As[k][ty << 2];
      const float4 b = *(const float4*)&Bs[k][tx << 2];
      acc[0][0] += a.x * b.x; acc[0][1] += a.x * b.y; acc[0][2] += a.x * b.z; acc[0][3] += a.x * b.w;
      acc[1][0] += a.y * b.x; acc[1][1] += a.y * b.y; acc[1][2] += a.y * b.z; acc[1][3] += a.y * b.w;
      acc[2][0] += a.z * b.x; acc[2][1] += a.z * b.y; acc[2][2] += a.z * b.z; acc[2][3] += a.z * b.w;
      acc[3][0] += a.w * b.x; acc[3][1] += a.w * b.y; acc[3][2] += a.w * b.z; acc[3][3] += a.w * b.w;
      if (MODE == 2) {
        const float4 b2 = *(const float4*)&Bs2[k][tx << 2];
        acc2[0][0] += a.x * b2.x; acc2[0][1] += a.x * b2.y; acc2[0][2] += a.x * b2.z; acc2[0][3] += a.x * b2.w;
        acc2[1][0] += a.y * b2.x; acc2[1][1] += a.y * b2.y; acc2[1][2] += a.y * b2.z; acc2[1][3] += a.y * b2.w;
        acc2[2][0] += a.z * b2.x; acc2[2][1] += a.z * b2.y; acc2[2][2] += a.z * b2.z; acc2[2][3] += a.z * b2.w;
        acc2[3][0] += a.w * b2.x; acc2[3][1] += a.w * b2.y; acc2[3][2] += a.w * b2.z; acc2[3][3] += a.w * b2.w;
      }
    }
  }
#pragma unroll
  for (int i = 0; i < 4; ++i) {
    const int row = m0 + (ty << 2) + i;
    float o0 = acc[i][0], o1 = acc[i][1], o2 = acc[i][2], o3 = acc[i][3];
    if (MODE == 2) {
      o0 = o0 / (1.f + __expf(-o0)) * acc2[i][0];
      o1 = o1 / (1.f + __expf(-o1)) * acc2[i][1];
      o2 = o2 / (1.f + __expf(-o2)) * acc2[i][2];
      o3 = o3 / (1.f + __expf(-o3)) * acc2[i][3];
    }
    if (MODE == 1) {
      const float4 rv = *(const float4*)&R[(size_t)row * N + n0 + (tx << 2)];
      o0 += rv.x; o1 += rv.y; o2 += rv.z; o3 += rv.w;
    }
    const float4 ov = {o0, o1, o2, o3};
    *(float4*)&C[(size_t)row * N + n0 + (tx << 2)] = ov;
  }
}

extern "C" void kernel_launch(void* const* d_in, const int* in_sizes, int n_in,
                              void* d_out, int out_size, void* d_ws, size_t ws_size,
                              hipStream_t stream) {
  const float* x  = (const float*)d_in[0];
  const float* Wq = (const float*)d_in[1];
  const float* Wk = (const float*)d_in[2];
  const float* Wv = (const float*)d_in[3];
  const float* Wo = (const float*)d_in[4];
  const float* g1 = (const float*)d_in[5];
  const float* g2 = (const float*)d_in[6];
  const float* W1 = (const float*)d_in[7];
  const float* W2 = (const float*)d_in[8];
  const float* W3 = (const float*)d_in[9];
  float* out = (float*)d_out;
  float* ws = (float*)d_ws;

  const size_t SEG = (size_t)ROWS * D_MODEL;  // 4,194,304 floats
  float* h  = ws;            // segment 0: h, then ctx, then h2 (sequentially dead/reborn)
  float* Qb = ws + SEG;      // segment 1
  float* Kb = ws + 2 * SEG;  // segment 2
  float* Vb = ws + 3 * SEG;  // segment 3
  float* gb = ws + SEG;      // SwiGLU gate buffer: 4*SEG floats, overlays dead Q/K/V
                             // total ws use: 5*SEG floats = 84 MB

  // 1. h = rmsnorm(x, g1)
  rmsnorm_k<<<ROWS, 256, 0, stream>>>(x, g1, h);
  // 2. Q,K,V = h @ Wq/Wk/Wv   (layout [B*S, D] with heads as column slices)
  gemm_k<0><<<dim3(16, 64), 256, 0, stream>>>(h, Wq, nullptr, nullptr, Qb, ROWS, D_MODEL, D_MODEL);
  gemm_k<0><<<dim3(16, 64), 256, 0, stream>>>(h, Wk, nullptr, nullptr, Kb, ROWS, D_MODEL, D_MODEL);
  gemm_k<0><<<dim3(16, 64), 256, 0, stream>>>(h, Wv, nullptr, nullptr, Vb, ROWS, D_MODEL, D_MODEL);
  // 3. RoPE(Q,K) in place
  rope_k<<<(ROWS * 512) / 256, 256, 0, stream>>>(Qb, Kb);
  // 4. ctx = causal_attention(Q,K,V)   (ctx reuses h's segment)
  attn_k<<<dim3(SEQ / 64, 2 * NH), 256, 0, stream>>>(Qb, Kb, Vb, h);
  // 5. out1 = x + ctx @ Wo  -> d_out
  gemm_k<1><<<dim3(16, 64), 256, 0, stream>>>(h, Wo, nullptr, x, out, ROWS, D_MODEL, D_MODEL);
  // 6. h2 = rmsnorm(out1, g2)  (reuses segment 0)
  rmsnorm_k<<<ROWS, 256, 0, stream>>>(out, g2, h);
  // 7. gb = silu(h2@W1) * (h2@W3)
  gemm_k<2><<<dim3(64, 64), 256, 0, stream>>>(h, W1, W3, nullptr, gb, ROWS, DFF, D_MODEL);
  // 8. out = out1 + gb @ W2
  gemm_k<1><<<dim3(16, 64), 256, 0, stream>>>(gb, W2, nullptr, out, out, ROWS, D_MODEL, DFF);
}

// Round 3
// 515.683 us; speedup vs baseline: 8.1220x; 8.1220x over previous
//
#include <hip/hip_runtime.h>
#include <math.h>

typedef unsigned short ushort_t;
typedef __attribute__((ext_vector_type(8))) short short8;
typedef __attribute__((ext_vector_type(4))) float f32x4;

#define MFMA16(a, b, c) __builtin_amdgcn_mfma_f32_16x16x32_bf16((a), (b), (c), 0, 0, 0)

static __device__ __forceinline__ ushort_t f2bf(float f) {
  unsigned int u = __float_as_uint(f);
  u = u + 0x7FFFu + ((u >> 16) & 1u);  // RTNE
  return (ushort_t)(u >> 16);
}
static __device__ __forceinline__ float bf2f(ushort_t s) {
  return __uint_as_float(((unsigned int)s) << 16);
}

// ---------------- RMSNorm fp32 in -> bf16 out ----------------
__global__ __launch_bounds__(256) void rmsnorm_k(const float* __restrict__ x,
                                                 const float* __restrict__ g,
                                                 ushort_t* __restrict__ o) {
  const int r = blockIdx.x, t = threadIdx.x;
  const float4 xv = ((const float4*)(x + (size_t)r * 1024))[t];
  float ss = xv.x * xv.x + xv.y * xv.y + xv.z * xv.z + xv.w * xv.w;
#pragma unroll
  for (int m = 32; m >= 1; m >>= 1) ss += __shfl_xor(ss, m);
  __shared__ float wp[4];
  if ((t & 63) == 0) wp[t >> 6] = ss;
  __syncthreads();
  const float inv = rsqrtf((wp[0] + wp[1] + wp[2] + wp[3]) * (1.f / 1024.f) + 1e-5f);
  const float4 gv = ((const float4*)g)[t];
  ushort4 ov = {f2bf(xv.x * inv * gv.x), f2bf(xv.y * inv * gv.y),
                f2bf(xv.z * inv * gv.z), f2bf(xv.w * inv * gv.w)};
  *(ushort4*)(o + (size_t)r * 1024 + t * 4) = ov;
}

// ---------------- transpose + cast: fp32 [R][C] -> bf16 [C][R] ----------------
__global__ __launch_bounds__(256) void transpose_cast_k(const float* __restrict__ in,
                                                        ushort_t* __restrict__ out,
                                                        int R, int C) {
  __shared__ ushort_t Ts[64][72];
  const int t = threadIdx.x;
  const int c0 = blockIdx.x * 64, r0 = blockIdx.y * 64;
  const int lr = t >> 4, lc = (t & 15) * 4;
#pragma unroll
  for (int i = 0; i < 4; ++i) {
    const float4 v = *(const float4*)&in[(size_t)(r0 + lr + i * 16) * C + c0 + lc];
    Ts[lr + i * 16][lc + 0] = f2bf(v.x);
    Ts[lr + i * 16][lc + 1] = f2bf(v.y);
    Ts[lr + i * 16][lc + 2] = f2bf(v.z);
    Ts[lr + i * 16][lc + 3] = f2bf(v.w);
  }
  __syncthreads();
  const int rr = (t & 15) * 4;
#pragma unroll
  for (int i = 0; i < 4; ++i) {
    const int cc = (t >> 4) + i * 16;
    ushort4 o = {Ts[rr + 0][cc], Ts[rr + 1][cc], Ts[rr + 2][cc], Ts[rr + 3][cc]};
    *(ushort4*)&out[(size_t)(c0 + cc) * R + r0 + rr] = o;
  }
}

// ---------------- RoPE in-place on bf16, ld=3072; scale folded (Q: 0.125) ----------------
__global__ __launch_bounds__(256) void rope_k(ushort_t* __restrict__ buf, float scale) {
  const int idx = blockIdx.x * 256 + threadIdx.x;  // 4096*16*8
  const int row = idx >> 7, rem = idx & 127;
  const int head = rem >> 3, gq = rem & 7;
  const int i0 = gq * 4;
  const int s = row & 2047;
  ushort_t* p = buf + (size_t)row * 3072 + head * 64 + i0 * 2;
  uint4 v = *(uint4*)p;
  ushort_t* e = (ushort_t*)&v;
#pragma unroll
  for (int k = 0; k < 4; ++k) {
    const float ang = (float)s * expf(-(float)(i0 + k) * 0.28782313662425572f);  // ln(1e4)/32
    float sn, cs;
    sincosf(ang, &sn, &cs);
    const float x1 = bf2f(e[2 * k]), x2 = bf2f(e[2 * k + 1]);
    e[2 * k] = f2bf((x1 * cs - x2 * sn) * scale);
    e[2 * k + 1] = f2bf((x2 * cs + x1 * sn) * scale);
  }
  *(uint4*)p = v;
}

// ---------------- MFMA GEMM: A[M][K] bf16, Bt[N][K] bf16 ----------------
// MODE 0: C=bf16(A@B). MODE 1: C=fp32(A@B + R). MODE 2: C=bf16(silu(A@B1)*(A@B2)).
// 128x128 tile, BK=32, 4 waves (2x2 of 64x64), 16x16x32 MFMA.
template <int MODE>
__global__ __launch_bounds__(256) void gemm_k(const ushort_t* __restrict__ A,
                                              const ushort_t* __restrict__ Bt,
                                              const ushort_t* __restrict__ Bt2,
                                              const float* __restrict__ R,
                                              void* __restrict__ C,
                                              int N, int K) {
  __shared__ uint4 smem[(MODE == 2 ? 24576 : 16384) / 16];
  char* sm = (char*)smem;
  const int t = threadIdx.x, lane = t & 63, w = t >> 6;
  const int g = lane >> 4, li = lane & 15;
  const int wr = w >> 1, wc = w & 1;
  const int n0 = blockIdx.x * 128, m0 = blockIdx.y * 128;
  const int srow = t >> 1, sh = t & 1;
  f32x4 acc[4][4] = {};
  f32x4 acc2[4][4] = {};
  const int nkt = K >> 5;
  for (int kt = 0; kt < nkt; ++kt) {
    __syncthreads();
    {
      const ushort_t* ga = A + (size_t)(m0 + srow) * K + kt * 32 + sh * 16;
      const uint4 a0 = *(const uint4*)ga, a1 = *(const uint4*)(ga + 8);
      *(uint4*)(sm + srow * 64 + sh * 32) = a0;
      *(uint4*)(sm + srow * 64 + sh * 32 + 16) = a1;
      const ushort_t* gb = Bt + (size_t)(n0 + srow) * K + kt * 32 + sh * 16;
      const uint4 b0 = *(const uint4*)gb, b1 = *(const uint4*)(gb + 8);
      *(uint4*)(sm + 8192 + srow * 64 + sh * 32) = b0;
      *(uint4*)(sm + 8192 + srow * 64 + sh * 32 + 16) = b1;
      if (MODE == 2) {
        const ushort_t* gc = Bt2 + (size_t)(n0 + srow) * K + kt * 32 + sh * 16;
        const uint4 c0 = *(const uint4*)gc, c1 = *(const uint4*)(gc + 8);
        *(uint4*)(sm + 16384 + srow * 64 + sh * 32) = c0;
        *(uint4*)(sm + 16384 + srow * 64 + sh * 32 + 16) = c1;
      }
    }
    __syncthreads();
    short8 af[4], bfr[4], bfr2[4];
#pragma unroll
    for (int mi = 0; mi < 4; ++mi)
      af[mi] = *(const short8*)(sm + (wr * 64 + mi * 16 + li) * 64 + g * 16);
#pragma unroll
    for (int ni = 0; ni < 4; ++ni)
      bfr[ni] = *(const short8*)(sm + 8192 + (wc * 64 + ni * 16 + li) * 64 + g * 16);
    if (MODE == 2) {
#pragma unroll
      for (int ni = 0; ni < 4; ++ni)
        bfr2[ni] = *(const short8*)(sm + 16384 + (wc * 64 + ni * 16 + li) * 64 + g * 16);
    }
#pragma unroll
    for (int mi = 0; mi < 4; ++mi)
#pragma unroll
      for (int ni = 0; ni < 4; ++ni) {
        acc[mi][ni] = MFMA16(af[mi], bfr[ni], acc[mi][ni]);
        if (MODE == 2) acc2[mi][ni] = MFMA16(af[mi], bfr2[ni], acc2[mi][ni]);
      }
  }
#pragma unroll
  for (int mi = 0; mi < 4; ++mi)
#pragma unroll
    for (int ni = 0; ni < 4; ++ni)
#pragma unroll
      for (int r = 0; r < 4; ++r) {
        const int row = m0 + wr * 64 + mi * 16 + g * 4 + r;
        const int col = n0 + wc * 64 + ni * 16 + li;
        float v = acc[mi][ni][r];
        if (MODE == 2) {
          const float a2 = acc2[mi][ni][r];
          v = v / (1.f + __expf(-v)) * a2;
        }
        if (MODE == 1)
          ((float*)C)[(size_t)row * N + col] = v + R[(size_t)row * N + col];
        else
          ((ushort_t*)C)[(size_t)row * N + col] = f2bf(v);
      }
}

// ---------------- MFMA flash attention (causal), bf16 QKV packed ld=3072 ----------------
// grid (S/64=32, B*H=32), 256 thr = 4 waves, wave w owns q-rows [q0+16w, +16).
// LDS: Ks [64key][64dh] swz | Vt [64dh][64key] swz | Ps per-wave [16q][64key] swz.
__global__ __launch_bounds__(256) void attn_k(const ushort_t* __restrict__ qkv,
                                              ushort_t* __restrict__ ctx) {
  __shared__ uint4 smemv[24576 / 16];
  char* sm = (char*)smemv;
  const int qt = blockIdx.x, bh = blockIdx.y;
  const int b = bh >> 4, h = bh & 15;
  const int t = threadIdx.x, lane = t & 63, w = t >> 6;
  const int g = lane >> 4, li = lane & 15;
  const int rowb = b * 2048;
  const size_t qbase = (size_t)rowb * 3072 + h * 64;
  const int q0 = qt * 64;

  short8 qa[2];
  {
    const int qrow = q0 + w * 16 + li;
    qa[0] = *(const short8*)(qkv + qbase + (size_t)qrow * 3072 + 8 * g);
    qa[1] = *(const short8*)(qkv + qbase + (size_t)qrow * 3072 + 32 + 8 * g);
  }
  f32x4 acc[4] = {};
  float mr[4], lr[4];
#pragma unroll
  for (int r = 0; r < 4; ++r) { mr[r] = -INFINITY; lr[r] = 0.f; }

  const int srow = t >> 2, sc = t & 3;
  for (int kt = 0; kt <= qt; ++kt) {
    __syncthreads();
    {  // stage K rows (full 128B per row: 16 elems/thread) and V^T (scatter), both swizzled
      const ushort_t* kp = qkv + qbase + 1024 + (size_t)(kt * 64 + srow) * 3072 + sc * 16;
      const uint4 k0 = *(const uint4*)kp, k1 = *(const uint4*)(kp + 8);
      *(uint4*)(sm + srow * 128 + ((sc * 32) ^ ((srow & 7) << 4))) = k0;
      *(uint4*)(sm + srow * 128 + ((sc * 32 + 16) ^ ((srow & 7) << 4))) = k1;
      const ushort_t* vp = qkv + qbase + 2048 + (size_t)(kt * 64 + srow) * 3072 + sc * 16;
      ushort_t tmp[16];
      *(uint4*)tmp = *(const uint4*)vp;
      *(uint4*)(tmp + 8) = *(const uint4*)(vp + 8);
#pragma unroll
      for (int e = 0; e < 16; ++e) {
        const int dh = sc * 16 + e;
        *(ushort_t*)(sm + 8192 + dh * 128 + ((2 * srow) ^ ((dh & 7) << 4))) = tmp[e];
      }
    }
    __syncthreads();
    // QK^T: s[nt] covers keys nt*16+li, q-rows g*4+r (wave-local)
    f32x4 s[4];
#pragma unroll
    for (int nt = 0; nt < 4; ++nt) {
      const int key = nt * 16 + li;
      const short8 kb0 = *(const short8*)(sm + key * 128 + ((16 * g) ^ ((key & 7) << 4)));
      const short8 kb1 = *(const short8*)(sm + key * 128 + ((64 + 16 * g) ^ ((key & 7) << 4)));
      f32x4 z = {0.f, 0.f, 0.f, 0.f};
      z = MFMA16(qa[0], kb0, z);
      z = MFMA16(qa[1], kb1, z);
      s[nt] = z;
    }
    if (kt == qt) {  // causal mask on diagonal tile
#pragma unroll
      for (int nt = 0; nt < 4; ++nt)
#pragma unroll
        for (int r = 0; r < 4; ++r) {
          const int key = kt * 64 + nt * 16 + li;
          const int qq = q0 + w * 16 + g * 4 + r;
          if (key > qq) s[nt][r] = -INFINITY;
        }
    }
    // online softmax (reduce over 16-lane groups: masks 1,2,4,8)
#pragma unroll
    for (int r = 0; r < 4; ++r) {
      float tm = fmaxf(fmaxf(s[0][r], s[1][r]), fmaxf(s[2][r], s[3][r]));
#pragma unroll
      for (int m = 8; m >= 1; m >>= 1) tm = fmaxf(tm, __shfl_xor(tm, m));
      const float nm = fmaxf(mr[r], tm);
      const float rs = __expf(mr[r] - nm);
      mr[r] = nm;
      float ps = 0.f;
#pragma unroll
      for (int nt = 0; nt < 4; ++nt) {
        const float p = __expf(s[nt][r] - nm);
        s[nt][r] = p;
        ps += p;
      }
#pragma unroll
      for (int m = 8; m >= 1; m >>= 1) ps += __shfl_xor(ps, m);
      lr[r] = lr[r] * rs + ps;
#pragma unroll
      for (int dt = 0; dt < 4; ++dt) acc[dt][r] *= rs;
    }
    // write P (bf16) to wave-private LDS, swizzled
#pragma unroll
    for (int nt = 0; nt < 4; ++nt)
#pragma unroll
      for (int r = 0; r < 4; ++r) {
        const int q = g * 4 + r;
        const int colb = 2 * (nt * 16 + li);
        *(ushort_t*)(sm + 16384 + w * 2048 + q * 128 + (colb ^ ((q & 7) << 4))) = f2bf(s[nt][r]);
      }
    // PV
    short8 pa[2];
    pa[0] = *(const short8*)(sm + 16384 + w * 2048 + li * 128 + ((16 * g) ^ ((li & 7) << 4)));
    pa[1] = *(const short8*)(sm + 16384 + w * 2048 + li * 128 + ((64 + 16 * g) ^ ((li & 7) << 4)));
#pragma unroll
    for (int dt = 0; dt < 4; ++dt) {
      const int dh = dt * 16 + li;
      const short8 vb0 = *(const short8*)(sm + 8192 + dh * 128 + ((16 * g) ^ ((dh & 7) << 4)));
      const short8 vb1 = *(const short8*)(sm + 8192 + dh * 128 + ((64 + 16 * g) ^ ((dh & 7) << 4)));
      acc[dt] = MFMA16(pa[0], vb0, acc[dt]);
      acc[dt] = MFMA16(pa[1], vb1, acc[dt]);
    }
  }
#pragma unroll
  for (int dt = 0; dt < 4; ++dt)
#pragma unroll
    for (int r = 0; r < 4; ++r) {
      const int row = rowb + q0 + w * 16 + g * 4 + r;
      const int col = h * 64 + dt * 16 + li;
      ctx[(size_t)row * 1024 + col] = f2bf(acc[dt][r] / lr[r]);
    }
}

extern "C" void kernel_launch(void* const* d_in, const int* in_sizes, int n_in,
                              void* d_out, int out_size, void* d_ws, size_t ws_size,
                              hipStream_t stream) {
  const float* x = (const float*)d_in[0];
  const float* Wq = (const float*)d_in[1];
  const float* Wk = (const float*)d_in[2];
  const float* Wv = (const float*)d_in[3];
  const float* Wo = (const float*)d_in[4];
  const float* g1 = (const float*)d_in[5];
  const float* g2 = (const float*)d_in[6];
  const float* W1 = (const float*)d_in[7];
  const float* W2 = (const float*)d_in[8];
  const float* W3 = (const float*)d_in[9];
  float* out = (float*)d_out;

  char* wsb = (char*)d_ws;
  ushort_t* hb = (ushort_t*)(wsb);                         // 8 MiB
  ushort_t* qkv = (ushort_t*)(wsb + (8u << 20));           // 24 MiB
  ushort_t* ctx = (ushort_t*)(wsb + (32u << 20));          // 8 MiB
  ushort_t* gbuf = (ushort_t*)(wsb + (8u << 20));          // 32 MiB, overlays dead qkv+ctx
  ushort_t* wqkvT = (ushort_t*)(wsb + (40u << 20));        // 6 MiB
  ushort_t* woT = (ushort_t*)(wsb + (46u << 20));          // 2 MiB
  ushort_t* w13T = (ushort_t*)(wsb + (48u << 20));         // 16 MiB
  ushort_t* w2T = (ushort_t*)(wsb + (64u << 20));          // 8 MiB

  // weight transpose+cast to bf16 [N][K]
  transpose_cast_k<<<dim3(16, 16), 256, 0, stream>>>(Wq, wqkvT, 1024, 1024);
  transpose_cast_k<<<dim3(16, 16), 256, 0, stream>>>(Wk, wqkvT + 1024 * 1024, 1024, 1024);
  transpose_cast_k<<<dim3(16, 16), 256, 0, stream>>>(Wv, wqkvT + 2 * 1024 * 1024, 1024, 1024);
  transpose_cast_k<<<dim3(16, 16), 256, 0, stream>>>(Wo, woT, 1024, 1024);
  transpose_cast_k<<<dim3(64, 16), 256, 0, stream>>>(W1, w13T, 1024, 4096);
  transpose_cast_k<<<dim3(64, 16), 256, 0, stream>>>(W3, w13T + 4096 * 1024, 1024, 4096);
  transpose_cast_k<<<dim3(16, 64), 256, 0, stream>>>(W2, w2T, 4096, 1024);

  // 1. h = rmsnorm(x, g1) -> bf16
  rmsnorm_k<<<4096, 256, 0, stream>>>(x, g1, hb);
  // 2. qkv = h @ [Wq|Wk|Wv]
  gemm_k<0><<<dim3(24, 32), 256, 0, stream>>>(hb, wqkvT, nullptr, nullptr, qkv, 3072, 1024);
  // 3. RoPE (Q gets 1/sqrt(dh) folded in)
  rope_k<<<2048, 256, 0, stream>>>(qkv, 0.125f);
  rope_k<<<2048, 256, 0, stream>>>(qkv + 1024, 1.0f);
  // 4. ctx = causal flash attention
  attn_k<<<dim3(32, 32), 256, 0, stream>>>(qkv, ctx);
  // 5. out1 = x + ctx @ Wo  (fp32)
  gemm_k<1><<<dim3(8, 32), 256, 0, stream>>>(ctx, woT, nullptr, x, out, 1024, 1024);
  // 6. h2 = rmsnorm(out1, g2) -> bf16
  rmsnorm_k<<<4096, 256, 0, stream>>>(out, g2, hb);
  // 7. gbuf = silu(h2@W1) * (h2@W3)
  gemm_k<2><<<dim3(32, 32), 256, 0, stream>>>(hb, w13T, w13T + 4096 * 1024, nullptr, gbuf, 4096, 1024);
  // 8. out = out1 + gbuf @ W2
  gemm_k<1><<<dim3(8, 32), 256, 0, stream>>>(gbuf, w2T, nullptr, out, out, 1024, 4096);
}